// Round 5
// baseline (853.832 us; speedup 1.0000x reference)
//
#include <hip/hip_runtime.h>
#include <hip/hip_bf16.h>
#include <stdint.h>

#define S_N 10000
#define MPAD 10112
#define B_N 2048
#define F_N 128

typedef __bf16 bf16x8 __attribute__((ext_vector_type(8)));
typedef __bf16 bf16x4 __attribute__((ext_vector_type(4)));
typedef float  f32x4  __attribute__((ext_vector_type(4)));
typedef unsigned long long u64;
typedef unsigned int u32;
typedef unsigned short u16;

union Bf8 { u16 us[8]; bf16x8 v; };
union Bh8 { __bf16 h[8]; bf16x8 v; };

__device__ __forceinline__ float lrelu02(float x) { return x >= 0.0f ? x : 0.2f * x; }
__device__ __forceinline__ float eluf(float x)    { return x > 0.0f ? x : expm1f(x); }

// ---------------- K1: adjacency bits + SfB + W2T + h1T/q + (ticketed) YT/ZT ----------------
// blocks 0..1279: mask gather/transpose (+ last-of-wb computes YT/ZT); 1280..6335: SfB;
// 6336..6591: W2T; 6592..6655: h1T/q
__global__ __launch_bounds__(256) void k_pre(const int* __restrict__ adj_c,
        const int* __restrict__ adj_p, const int* __restrict__ src,
        const float* __restrict__ Sfeat, const float* __restrict__ Rfeat,
        const float* __restrict__ W1, const float* __restrict__ W2, const float* __restrict__ a,
        u64* __restrict__ tcity, u64* __restrict__ tprov,
        u32* __restrict__ cc, u32* __restrict__ pc, u32* __restrict__ tick2,
        __bf16* __restrict__ SfB, __bf16* __restrict__ W2T, __bf16* __restrict__ h1T,
        float* __restrict__ q, __bf16* __restrict__ YT, __bf16* __restrict__ ZT) {
    const int bid = blockIdx.x, t = threadIdx.x;
    if (bid < 1280) {
        const int sc = bid % 20, wb = (bid / 20) % 32, mat = bid / 640;
        const int l = t & 63, w = t >> 6;
        const int* adj = mat ? adj_p : adj_c;
        u64* tb = mat ? tprov : tcity;
        u32* cnt = mat ? pc : cc;
        __shared__ u64 wt[64][8];
        __shared__ u32 lc[64];
        __shared__ float icc[64], ipc[64];
        __shared__ u32 lastv;
        if (t < 64) lc[t] = 0;
        __syncthreads();
        const int s1 = sc * 512 + t;
        const int s2 = s1 + 256;
        for (int bb = 0; bb < 64; ++bb) {
            int row = src[wb * 64 + bb];
            const int* rp = adj + (size_t)row * S_N;
            int v1 = (s1 < S_N) ? rp[s1] : 0;
            int v2 = (s2 < S_N) ? rp[s2] : 0;
            u64 b1 = __ballot(v1 > 0);
            u64 b2 = __ballot(v2 > 0);
            if (l == 0) {
                wt[bb][w] = b1;
                wt[bb][w + 4] = b2;
                atomicAdd(&lc[bb], (u32)(__popcll(b1) + __popcll(b2)));
            }
        }
        __syncthreads();
        if (t < 64) atomicAdd(&cnt[wb * 64 + t], lc[t]);
        for (int tile = w; tile < 8; tile += 4) {
            u64 wv = wt[l][tile];
            u64 myw = 0;
            #pragma unroll
            for (int j = 0; j < 64; ++j) {
                u64 bal = __ballot((int)((wv >> j) & 1ull));
                if (l == j) myw = bal;
            }
            int s = sc * 512 + tile * 64 + l;
            if (s < MPAD) tb[(size_t)wb * MPAD + s] = myw;
        }
        // ticket: last of the 40 blocks (20 sc x 2 mats) for this wb builds YT/ZT slice
        __syncthreads();
        if (t == 0) {
            __threadfence();
            lastv = atomicAdd(&tick2[wb], 1u);
        }
        __syncthreads();
        if (lastv == 39u) {
            __threadfence();
            if (t < 64) {
                u32 c1 = cc[wb * 64 + t], p1 = pc[wb * 64 + t];
                icc[t] = c1 ? 1.0f / (float)c1 : 0.0f;
                ipc[t] = p1 ? 1.0f / (float)p1 : 0.0f;
            }
            __syncthreads();
            for (int i = t; i < 8192; i += 256) {
                int bl = i & 63, f = i >> 6;
                int b = wb * 64 + bl;
                float sv = Sfeat[src[b] * F_N + f];
                YT[f * B_N + b] = (__bf16)(sv * icc[bl]);
                ZT[f * B_N + b] = (__bf16)(sv * ipc[bl]);
            }
        }
    } else if (bid < 6336) {
        int i = (bid - 1280) * 256 + t; // MPAD*128
        int s = i >> 7;
        SfB[i] = (__bf16)(s < S_N ? Sfeat[i] : 0.0f);
    } else if (bid < 6592) {
        int idx = (bid - 6336) * 256 + t; // 65536
        int hn = idx >> 7, k = idx & 127;
        int h = hn >> 7, n = hn & 127;
        W2T[idx] = (__bf16)W2[(h * F_N + k) * F_N + n];
    } else {
        __shared__ float red[256];
        int b2i = bid - 6592;
        int h = b2i >> 4, r = b2i & 15;
        float hv = 0.0f;
        if (t < 128) {
            const float* rf = Rfeat + r * F_N;
            const float* wp = W1 + h * F_N * F_N + t;
            for (int k = 0; k < F_N; ++k) hv += rf[k] * wp[k * F_N];
        }
        red[t] = (t < 128) ? hv * a[h * 256 + t] : 0.0f;
        __syncthreads();
        for (int off = 128; off > 0; off >>= 1) {
            if (t < off) red[t] += red[t + off];
            __syncthreads();
        }
        if (t == 0) q[h * 16 + r] = red[0];
        if (t < 128) {
            h1T[(h * F_N + t) * 32 + r] = (__bf16)hv;
            h1T[(h * F_N + t) * 32 + 16 + r] = (__bf16)0.0f;
        }
    }
}

// ---------------- G1: combined dispatch — g_T (blocks 0..315) || g_h2attM (316..631) ------
__global__ __launch_bounds__(256) void g_TH(const __bf16* __restrict__ YT, const __bf16* __restrict__ ZT,
        const u64* __restrict__ tcity, const u64* __restrict__ tprov,
        float* __restrict__ Tp, u32* __restrict__ tick, __bf16* __restrict__ Tb,
        const __bf16* __restrict__ A, const __bf16* __restrict__ W2T,
        const float* __restrict__ a, const float* __restrict__ q, const int* __restrict__ inter,
        __bf16* __restrict__ attb, float* __restrict__ Mg) {
    __shared__ __align__(16) char smraw[39680];
    const int t = threadIdx.x, l = t & 63, w = t >> 6;
    const int quad = l >> 4, ln = l & 15;
    const f32x4 fz = {0.0f, 0.0f, 0.0f, 0.0f};
    if (blockIdx.x < 316) {
        // ---------------- g_T: T split-K partials + last-block reduce -> Tb bf16 ----------
        const int xb = blockIdx.x >> 2, ky = blockIdx.x & 3;
        const int wm = w >> 1, wn = w & 1;
        const int s_blk = xb * 128;
        const unsigned char* cb = (const unsigned char*)tcity;
        const unsigned char* pb = (const unsigned char*)tprov;
        f32x4 acc[4][4];
        #pragma unroll
        for (int mt = 0; mt < 4; ++mt)
            #pragma unroll
            for (int nt = 0; nt < 4; ++nt) acc[mt][nt] = fz;
        const int k_base = ky * 512;
        for (int it = 0; it < 16; ++it) {
            int kk = k_base + it * 32;
            bf16x8 Ya[4], Za[4];
            #pragma unroll
            for (int mt = 0; mt < 4; ++mt) {
                int f = wm * 64 + mt * 16 + ln;
                Ya[mt] = *(const bf16x8*)(YT + f * B_N + kk + quad * 8);
                Za[mt] = *(const bf16x8*)(ZT + f * B_N + kk + quad * 8);
            }
            bf16x8 Bc[4], Bp[4];
            #pragma unroll
            for (int nt = 0; nt < 4; ++nt) {
                int s = s_blk + wn * 64 + nt * 16 + ln;
                size_t base = ((size_t)(kk >> 6) * MPAD + s) * 8 + ((kk >> 3) & 7) + quad;
                unsigned int cby = cb[base], pby = pb[base];
                Bf8 uc, up;
                #pragma unroll
                for (int j = 0; j < 8; ++j) {
                    uc.us[j] = ((cby >> j) & 1u) ? (u16)0x3F80 : (u16)0;
                    up.us[j] = ((pby >> j) & 1u) ? (u16)0x3F80 : (u16)0;
                }
                Bc[nt] = uc.v; Bp[nt] = up.v;
            }
            #pragma unroll
            for (int mt = 0; mt < 4; ++mt)
                #pragma unroll
                for (int nt = 0; nt < 4; ++nt) {
                    acc[mt][nt] = __builtin_amdgcn_mfma_f32_16x16x32_bf16(Ya[mt], Bc[nt], acc[mt][nt], 0, 0, 0);
                    acc[mt][nt] = __builtin_amdgcn_mfma_f32_16x16x32_bf16(Za[mt], Bp[nt], acc[mt][nt], 0, 0, 0);
                }
        }
        float* tp = Tp + (size_t)ky * ((size_t)MPAD * F_N);
        #pragma unroll
        for (int nt = 0; nt < 4; ++nt) {
            int s = s_blk + wn * 64 + nt * 16 + ln;
            #pragma unroll
            for (int mt = 0; mt < 4; ++mt) {
                int f0 = wm * 64 + mt * 16 + quad * 4;
                *(f32x4*)(tp + (size_t)s * F_N + f0) = acc[mt][nt];
            }
        }
        u32* lastv = (u32*)smraw;
        __syncthreads();
        if (t == 0) {
            __threadfence();
            *lastv = atomicAdd(&tick[xb], 1u);
        }
        __syncthreads();
        if (*lastv == 3u) {
            __threadfence();
            const size_t stride = (size_t)MPAD * F_N;
            for (int idx = t; idx < 4096; idx += 256) {
                size_t off = (size_t)s_blk * F_N + (size_t)idx * 4;
                f32x4 v0 = *(const f32x4*)(Tp + off);
                f32x4 v1 = *(const f32x4*)(Tp + stride + off);
                f32x4 v2 = *(const f32x4*)(Tp + 2 * stride + off);
                f32x4 v3 = *(const f32x4*)(Tp + 3 * stride + off);
                f32x4 sum = v0 + v1 + v2 + v3;
                bf16x4 o;
                #pragma unroll
                for (int j = 0; j < 4; ++j) o[j] = (__bf16)sum[j];
                *(bf16x4*)(Tb + off) = o;
            }
        }
    } else {
        // ---------------- g_h2attM: h2 GEMM + att softmax + M-partial MFMA ---------------
        const int bid2 = blockIdx.x - 316;
        const int s0 = (bid2 >> 2) * 128, h = bid2 & 3;
        const int wm = w >> 1, wn = w & 1;
        __bf16* h2T  = (__bf16*)smraw;                 // [f][s_local] stride 136 (34816 B)
        __bf16* attT = (__bf16*)(smraw + 34816);       // [c][s_local] stride 136 (4352 B)
        float*  ps   = (float*)(smraw + 34816 + 4352); // 512 B
        if (t < 128) ps[t] = 0.0f;
        __syncthreads();
        f32x4 acc[4][4];
        #pragma unroll
        for (int mt = 0; mt < 4; ++mt)
            #pragma unroll
            for (int nt = 0; nt < 4; ++nt) acc[mt][nt] = fz;
        #pragma unroll
        for (int it = 0; it < 4; ++it) {
            int kk = it * 32;
            bf16x8 af[4], bfr[4];
            #pragma unroll
            for (int mt = 0; mt < 4; ++mt)
                af[mt] = *(const bf16x8*)(A + (size_t)(s0 + wm * 64 + mt * 16 + ln) * F_N + kk + quad * 8);
            #pragma unroll
            for (int nt = 0; nt < 4; ++nt)
                bfr[nt] = *(const bf16x8*)(W2T + (size_t)(h * F_N + wn * 64 + nt * 16 + ln) * F_N + kk + quad * 8);
            #pragma unroll
            for (int mt = 0; mt < 4; ++mt)
                #pragma unroll
                for (int nt = 0; nt < 4; ++nt)
                    acc[mt][nt] = __builtin_amdgcn_mfma_f32_16x16x32_bf16(af[mt], bfr[nt], acc[mt][nt], 0, 0, 0);
        }
        float a2v[4];
        #pragma unroll
        for (int nt = 0; nt < 4; ++nt) a2v[nt] = a[h * 256 + 128 + wn * 64 + nt * 16 + ln];
        #pragma unroll
        for (int mt = 0; mt < 4; ++mt) {
            #pragma unroll
            for (int nt = 0; nt < 4; ++nt) {
                bf16x4 o;
                #pragma unroll
                for (int j = 0; j < 4; ++j) o[j] = (__bf16)acc[mt][nt][j];
                *(bf16x4*)(&h2T[(wn * 64 + nt * 16 + ln) * 136 + wm * 64 + mt * 16 + quad * 4]) = o;
            }
            #pragma unroll
            for (int r = 0; r < 4; ++r) {
                float pp = 0.0f;
                #pragma unroll
                for (int nt = 0; nt < 4; ++nt) pp += acc[mt][nt][r] * a2v[nt];
                #pragma unroll
                for (int m = 8; m > 0; m >>= 1) pp += __shfl_xor(pp, m, 16);
                if (ln == 0) atomicAdd(&ps[wm * 64 + mt * 16 + quad * 4 + r], pp);
            }
        }
        __syncthreads();
        if (t < 128) {
            int s = s0 + t;
            if (s < S_N) {
                float pv = ps[t];
                float e[16];
                int msk[16], cn = 0;
                float mx = -3e38f;
                #pragma unroll
                for (int c = 0; c < 16; ++c) {
                    msk[c] = inter[s * 16 + c] > 0;
                    cn += msk[c];
                    e[c] = lrelu02(pv + q[h * 16 + c]);
                    if (msk[c]) mx = fmaxf(mx, e[c]);
                }
                float sm = 0.0f;
                #pragma unroll
                for (int c = 0; c < 16; ++c) {
                    e[c] = msk[c] ? expf(e[c] - mx) : 0.0f;
                    sm += e[c];
                }
                float inv = cn > 0 ? 1.0f / sm : 0.0f;
                #pragma unroll
                for (int c = 0; c < 16; ++c) {
                    float av = cn > 0 ? e[c] * inv : 0.0625f;
                    attb[((size_t)h * MPAD + s) * 16 + c] = (__bf16)av;
                    attT[c * 136 + t] = (__bf16)av;
                }
            } else {
                #pragma unroll
                for (int c = 0; c < 16; ++c) {
                    attb[((size_t)h * MPAD + s) * 16 + c] = (__bf16)0.0f;
                    attT[c * 136 + t] = (__bf16)0.0f;
                }
            }
        }
        __syncthreads();
        #pragma unroll
        for (int fi = 0; fi < 2; ++fi) {
            int ft = 2 * w + fi;
            f32x4 macc = fz;
            #pragma unroll
            for (int kit = 0; kit < 4; ++kit) {
                bf16x8 av = *(const bf16x8*)(&attT[ln * 136 + kit * 32 + quad * 8]);
                bf16x8 bv = *(const bf16x8*)(&h2T[(ft * 16 + ln) * 136 + kit * 32 + quad * 8]);
                macc = __builtin_amdgcn_mfma_f32_16x16x32_bf16(av, bv, macc, 0, 0, 0);
            }
            #pragma unroll
            for (int r = 0; r < 4; ++r)
                atomicAdd(&Mg[(h * 16 + quad * 4 + r) * F_N + ft * 16 + ln], macc[r]);
        }
    }
}

// ---------------- G2: P = T@W2 + att@h1 (bf16, LDS-staged store) + BN column sums ---------
__global__ __launch_bounds__(256) void g_P(const __bf16* __restrict__ Tb, const __bf16* __restrict__ W2T,
        const __bf16* __restrict__ attb, const __bf16* __restrict__ h1T,
        __bf16* __restrict__ P, float* __restrict__ usum, float* __restrict__ usq) {
    const int t = threadIdx.x, l = t & 63, w = t >> 6;
    const int wm = w >> 1, wn = w & 1, quad = l >> 4, ln = l & 15;
    const int s0 = blockIdx.x * 128, h = blockIdx.y;
    __shared__ __bf16 sP[128 * 136];
    __shared__ float lsum[128], lsq[128];
    if (t < 128) { lsum[t] = 0.0f; lsq[t] = 0.0f; }
    __syncthreads();
    const f32x4 fz = {0.0f, 0.0f, 0.0f, 0.0f};
    f32x4 acc[4][4];
    #pragma unroll
    for (int mt = 0; mt < 4; ++mt)
        #pragma unroll
        for (int nt = 0; nt < 4; ++nt) acc[mt][nt] = fz;
    {
        bf16x8 a2[4], b2[4];
        #pragma unroll
        for (int mt = 0; mt < 4; ++mt) {
            int s = s0 + wm * 64 + mt * 16 + ln;
            Bf8 az;
            az.v = *(const bf16x8*)(attb + ((size_t)h * MPAD + s) * 16 + (quad & 1) * 8);
            if (quad >= 2) {
                #pragma unroll
                for (int j = 0; j < 8; ++j) az.us[j] = 0;
            }
            a2[mt] = az.v;
        }
        #pragma unroll
        for (int nt = 0; nt < 4; ++nt) {
            int f = wn * 64 + nt * 16 + ln;
            b2[nt] = *(const bf16x8*)(h1T + ((size_t)(h * F_N + f)) * 32 + quad * 8);
        }
        #pragma unroll
        for (int mt = 0; mt < 4; ++mt)
            #pragma unroll
            for (int nt = 0; nt < 4; ++nt)
                acc[mt][nt] = __builtin_amdgcn_mfma_f32_16x16x32_bf16(a2[mt], b2[nt], acc[mt][nt], 0, 0, 0);
    }
    #pragma unroll
    for (int it = 0; it < 4; ++it) {
        int kk = it * 32;
        bf16x8 af[4], bfr[4];
        #pragma unroll
        for (int mt = 0; mt < 4; ++mt)
            af[mt] = *(const bf16x8*)(Tb + (size_t)(s0 + wm * 64 + mt * 16 + ln) * F_N + kk + quad * 8);
        #pragma unroll
        for (int nt = 0; nt < 4; ++nt)
            bfr[nt] = *(const bf16x8*)(W2T + (size_t)(h * F_N + wn * 64 + nt * 16 + ln) * F_N + kk + quad * 8);
        #pragma unroll
        for (int mt = 0; mt < 4; ++mt)
            #pragma unroll
            for (int nt = 0; nt < 4; ++nt)
                acc[mt][nt] = __builtin_amdgcn_mfma_f32_16x16x32_bf16(af[mt], bfr[nt], acc[mt][nt], 0, 0, 0);
    }
    #pragma unroll
    for (int nt = 0; nt < 4; ++nt) {
        int f = wn * 64 + nt * 16 + ln;
        float p1 = 0.0f, p2 = 0.0f;
        #pragma unroll
        for (int mt = 0; mt < 4; ++mt) {
            int sb = wm * 64 + mt * 16 + quad * 4;
            #pragma unroll
            for (int r = 0; r < 4; ++r) {
                float val = acc[mt][nt][r];
                sP[(sb + r) * 136 + f] = (__bf16)val;
                p1 += val; p2 += val * val;
            }
        }
        atomicAdd(&lsum[f], p1);
        atomicAdd(&lsq[f], p2);
    }
    __syncthreads();
    if (t < 128) {
        atomicAdd(&usum[h * F_N + t], lsum[t]);
        atomicAdd(&usq[h * F_N + t], lsq[t]);
    }
    for (int g = t; g < 2048; g += 256) {
        int sl = g >> 4, fg = (g & 15) * 8;
        bf16x8 v = *(const bf16x8*)(&sP[sl * 136 + fg]);
        *(bf16x8*)(P + ((size_t)h * MPAD + s0 + sl) * F_N + fg) = v;
    }
}

// ---------------- G3: bn-finalize + G=elu(u@v^T) + final GAT layer + log_softmax ------
__global__ __launch_bounds__(256) void g_out(const __bf16* __restrict__ P,
        const float* __restrict__ usum, const float* __restrict__ usq, const float* __restrict__ Mg,
        const float* __restrict__ g1, const float* __restrict__ b1,
        const float* __restrict__ g2, const float* __restrict__ b2,
        const float* __restrict__ outW, const int* __restrict__ inter, float* __restrict__ out) {
    const int t = threadIdx.x, l = t & 63, w = t >> 6, quad = l >> 4, ln = l & 15;
    const int s0 = blockIdx.x * 32;
    __shared__ __bf16 v_lds[64 * 136];   // [h*16+r][f]
    __shared__ float G_lds[32 * 68];     // [s_local][h*16+r]
    __shared__ float scs[512], shs[512];
    __shared__ float W_lds[1024];
    for (int i = t; i < 1024; i += 256) W_lds[i] = outW[i];
    if (t < 128) {
        #pragma unroll
        for (int h = 0; h < 4; ++h) {
            int i = h * F_N + t;
            float mean = usum[i] * (1.0f / S_N);
            float var = usq[i] * (1.0f / S_N) - mean * mean;
            float sc = g2[i] * rsqrtf(var + 1e-5f);
            scs[i] = sc;
            shs[i] = b2[i] - mean * sc;
        }
    }
    {   // v = lrelu(bn1(M))
        int f = t & 127;
        int hb = (t >> 7) * 2;
        #pragma unroll
        for (int hh = hb; hh < hb + 2; ++hh) {
            float mv[16], sa = 0.0f, sb = 0.0f;
            #pragma unroll
            for (int r = 0; r < 16; ++r) {
                mv[r] = Mg[(hh * 16 + r) * F_N + f];
                sa += mv[r]; sb += mv[r] * mv[r];
            }
            float m1 = sa * 0.0625f, v1 = sb * 0.0625f - m1 * m1;
            int i = hh * F_N + f;
            float g = g1[i] * rsqrtf(v1 + 1e-5f);
            float bb = b1[i] - m1 * g;
            #pragma unroll
            for (int r = 0; r < 16; ++r)
                v_lds[(hh * 16 + r) * 136 + f] = (__bf16)lrelu02(mv[r] * g + bb);
        }
    }
    __syncthreads();
    const int h = w;
    const f32x4 fz = {0.0f, 0.0f, 0.0f, 0.0f};
    #pragma unroll
    for (int mt = 0; mt < 2; ++mt) {
        f32x4 gacc = fz;
        int s = s0 + mt * 16 + ln;
        #pragma unroll
        for (int kit = 0; kit < 4; ++kit) {
            int k0 = kit * 32 + quad * 8;
            bf16x8 pv = *(const bf16x8*)(P + ((size_t)h * MPAD + s) * F_N + k0);
            Bh8 af;
            #pragma unroll
            for (int j = 0; j < 8; ++j) {
                int f = k0 + j;
                af.h[j] = (__bf16)lrelu02((float)pv[j] * scs[h * F_N + f] + shs[h * F_N + f]);
            }
            bf16x8 bv = *(const bf16x8*)(&v_lds[(h * 16 + ln) * 136 + k0]);
            gacc = __builtin_amdgcn_mfma_f32_16x16x32_bf16(af.v, bv, gacc, 0, 0, 0);
        }
        #pragma unroll
        for (int r = 0; r < 4; ++r)
            G_lds[(mt * 16 + quad * 4 + r) * 68 + h * 16 + ln] = eluf(gacc[r]);
    }
    __syncthreads();
    const int c = t & 15, ss = t >> 4;
    #pragma unroll
    for (int pass = 0; pass < 2; ++pass) {
        int sl = pass * 16 + ss;
        int s = s0 + sl;
        float hm = 0.0f;
        #pragma unroll
        for (int j = 0; j < 64; ++j) hm += G_lds[sl * 68 + j] * W_lds[j * 16 + c];
        int valid = s < S_N;
        int msk = valid ? (inter[(valid ? s : 0) * 16 + c] > 0) : 0;
        int cn = msk;
        #pragma unroll
        for (int m = 8; m > 0; m >>= 1) cn += __shfl_xor(cn, m, 16);
        float attf = cn > 0 ? (msk ? 1.0f / (float)cn : 0.0f) : 0.0625f;
        float y = eluf(eluf(attf * hm));
        float mx = y;
        #pragma unroll
        for (int m = 8; m > 0; m >>= 1) mx = fmaxf(mx, __shfl_xor(mx, m, 16));
        float ex = expf(y - mx);
        float sm = ex;
        #pragma unroll
        for (int m = 8; m > 0; m >>= 1) sm += __shfl_xor(sm, m, 16);
        if (valid) out[s * 16 + c] = y - mx - logf(sm);
    }
}

extern "C" void kernel_launch(void* const* d_in, const int* in_sizes, int n_in,
                              void* d_out, int out_size, void* d_ws, size_t ws_size,
                              hipStream_t stream) {
    const int* inter = (const int*)d_in[0];
    const int* city  = (const int*)d_in[1];
    const int* prov  = (const int*)d_in[2];
    const int* src   = (const int*)d_in[3];
    const float* Sfeat = (const float*)d_in[4];
    const float* Rfeat = (const float*)d_in[5];
    const float* W1 = (const float*)d_in[6];
    const float* W2 = (const float*)d_in[7];
    const float* a  = (const float*)d_in[8];
    const float* g1 = (const float*)d_in[11];
    const float* b1 = (const float*)d_in[12];
    const float* g2 = (const float*)d_in[13];
    const float* b2 = (const float*)d_in[14];
    const float* outW = (const float*)d_in[15];
    float* out = (float*)d_out;

    char* p = (char*)d_ws;
    // ---- zeroed region ----
    float* M    = (float*)p; p += 4 * 16 * F_N * 4;   // 32768
    float* usum = (float*)p; p += 2048;
    float* usq  = (float*)p; p += 2048;
    u32*   cc   = (u32*)p;   p += 8192;
    u32*   pc   = (u32*)p;   p += 8192;
    u32*   tick = (u32*)p;   p += 512;                // 79 used
    u32*   tick2= (u32*)p;   p += 128;                // 32 used
    size_t zbytes = (size_t)(p - (char*)d_ws);        // 53888
    // ---- rest ----
    u64* tcity = (u64*)p; p += 32 * (size_t)MPAD * 8;
    u64* tprov = (u64*)p; p += 32 * (size_t)MPAD * 8;
    __bf16* YT  = (__bf16*)p; p += (size_t)F_N * B_N * 2;
    __bf16* ZT  = (__bf16*)p; p += (size_t)F_N * B_N * 2;
    __bf16* SfB = (__bf16*)p; p += (size_t)MPAD * F_N * 2;
    __bf16* W2T = (__bf16*)p; p += 512 * 128 * 2;
    __bf16* h1T = (__bf16*)p; p += 4 * 128 * 32 * 2;
    float*  q   = (float*)p;  p += 512;
    float*  Tp  = (float*)p;  p += 4 * (size_t)MPAD * F_N * 4;
    __bf16* Tb  = (__bf16*)p; p += (size_t)MPAD * F_N * 2;
    __bf16* attb= (__bf16*)p; p += 4 * (size_t)MPAD * 16 * 2;
    __bf16* P   = (__bf16*)p; p += 4 * (size_t)MPAD * F_N * 2;

    hipMemsetAsync(d_ws, 0, zbytes, stream);
    k_pre <<<6656, 256, 0, stream>>>(city, prov, src, Sfeat, Rfeat, W1, W2, a,
                                     tcity, tprov, cc, pc, tick2, SfB, W2T, h1T, q, YT, ZT);
    g_TH  <<<632, 256, 0, stream>>>(YT, ZT, tcity, tprov, Tp, tick, Tb,
                                    SfB, W2T, a, q, inter, attb, M);
    g_P   <<<dim3(79, 4), 256, 0, stream>>>(Tb, W2T, attb, h1T, P, usum, usq);
    g_out <<<316, 256, 0, stream>>>(P, usum, usq, M, g1, b1, g2, b2, outW, inter, out);
}

// Round 6
// 803.436 us; speedup vs baseline: 1.0627x; 1.0627x over previous
//
#include <hip/hip_runtime.h>
#include <hip/hip_bf16.h>
#include <stdint.h>

#define S_N 10000
#define MPAD 10112
#define B_N 2048
#define F_N 128

typedef __bf16 bf16x8 __attribute__((ext_vector_type(8)));
typedef __bf16 bf16x4 __attribute__((ext_vector_type(4)));
typedef float  f32x4  __attribute__((ext_vector_type(4)));
typedef unsigned long long u64;
typedef unsigned int u32;
typedef unsigned short u16;

union Bh8 { __bf16 h[8]; bf16x8 v; };

__device__ __forceinline__ float lrelu02(float x) { return x >= 0.0f ? x : 0.2f * x; }
__device__ __forceinline__ float eluf(float x)    { return x > 0.0f ? x : expm1f(x); }

// ---------------- K1: adjacency gather/bit-transpose + SfB + W2T + h1T/q ----------------
__global__ __launch_bounds__(256) void k_bits_pre(const int* __restrict__ adj_c,
        const int* __restrict__ adj_p, const int* __restrict__ src,
        const float* __restrict__ Sfeat, const float* __restrict__ Rfeat,
        const float* __restrict__ W1, const float* __restrict__ W2, const float* __restrict__ a,
        u64* __restrict__ tcity, u64* __restrict__ tprov,
        u32* __restrict__ cc, u32* __restrict__ pc,
        __bf16* __restrict__ SfB, __bf16* __restrict__ W2T, __bf16* __restrict__ h1T,
        float* __restrict__ q) {
    const int bid = blockIdx.x, t = threadIdx.x;
    if (bid < 1280) {
        const int sc = bid % 20, wb = (bid / 20) % 32, mat = bid / 640;
        const int l = t & 63, w = t >> 6;
        const int* adj = mat ? adj_p : adj_c;
        u64* tb = mat ? tprov : tcity;
        u32* cnt = mat ? pc : cc;
        __shared__ u64 wt[64][8];
        __shared__ u32 lc[64];
        if (t < 64) lc[t] = 0;
        __syncthreads();
        const int s1 = sc * 512 + t;
        const int s2 = s1 + 256;
        for (int bb = 0; bb < 64; ++bb) {
            int row = src[wb * 64 + bb];
            const int* rp = adj + (size_t)row * S_N;
            int v1 = (s1 < S_N) ? rp[s1] : 0;
            int v2 = (s2 < S_N) ? rp[s2] : 0;
            u64 b1 = __ballot(v1 > 0);
            u64 b2 = __ballot(v2 > 0);
            if (l == 0) {
                wt[bb][w] = b1;
                wt[bb][w + 4] = b2;
                atomicAdd(&lc[bb], (u32)(__popcll(b1) + __popcll(b2)));
            }
        }
        __syncthreads();
        if (t < 64) atomicAdd(&cnt[wb * 64 + t], lc[t]);
        for (int tile = w; tile < 8; tile += 4) {
            u64 wv = wt[l][tile];
            u64 myw = 0;
            #pragma unroll
            for (int j = 0; j < 64; ++j) {
                u64 bal = __ballot((int)((wv >> j) & 1ull));
                if (l == j) myw = bal;
            }
            int s = sc * 512 + tile * 64 + l;
            if (s < MPAD) tb[(size_t)wb * MPAD + s] = myw;
        }
    } else if (bid < 6336) {
        int i = (bid - 1280) * 256 + t; // MPAD*128
        int s = i >> 7;
        SfB[i] = (__bf16)(s < S_N ? Sfeat[i] : 0.0f);
    } else if (bid < 6592) {
        int idx = (bid - 6336) * 256 + t; // 65536
        int hn = idx >> 7, k = idx & 127;
        int h = hn >> 7, n = hn & 127;
        W2T[idx] = (__bf16)W2[(h * F_N + k) * F_N + n];
    } else {
        __shared__ float red[256];
        int b2i = bid - 6592;
        int h = b2i >> 4, r = b2i & 15;
        float hv = 0.0f;
        if (t < 128) {
            const float* rf = Rfeat + r * F_N;
            const float* wp = W1 + h * F_N * F_N + t;
            for (int k = 0; k < F_N; ++k) hv += rf[k] * wp[k * F_N];
        }
        red[t] = (t < 128) ? hv * a[h * 256 + t] : 0.0f;
        __syncthreads();
        for (int off = 128; off > 0; off >>= 1) {
            if (t < off) red[t] += red[t + off];
            __syncthreads();
        }
        if (t == 0) q[h * 16 + r] = red[0];
        if (t < 128) {
            h1T[(h * F_N + t) * 32 + r] = (__bf16)hv;
            h1T[(h * F_N + t) * 32 + 16 + r] = (__bf16)0.0f;
        }
    }
}

// ---------------- K2: Y^T/Z^T (needs counts from K1) ----------------
__global__ __launch_bounds__(256) void k_yz(const float* __restrict__ Sfeat,
        const int* __restrict__ src, const u32* __restrict__ cc, const u32* __restrict__ pc,
        __bf16* __restrict__ YT, __bf16* __restrict__ ZT) {
    int idx = blockIdx.x * 256 + threadIdx.x; // 128*2048
    int f = idx >> 11, b = idx & 2047;
    float sv = Sfeat[src[b] * F_N + f];
    float icc = cc[b] ? 1.0f / (float)cc[b] : 0.0f;
    float ipc = pc[b] ? 1.0f / (float)pc[b] : 0.0f;
    YT[f * B_N + b] = (__bf16)(sv * icc);
    ZT[f * B_N + b] = (__bf16)(sv * ipc);
}

// ---------------- G1: T split-K partials (LDS LUT unpack) + ticketed reduce -> Tb ---------
__global__ __launch_bounds__(256) void g_T(const __bf16* __restrict__ YT, const __bf16* __restrict__ ZT,
        const u64* __restrict__ tcity, const u64* __restrict__ tprov,
        float* __restrict__ Tp, u32* __restrict__ tick, __bf16* __restrict__ Tb) {
    const int t = threadIdx.x, l = t & 63, w = t >> 6;
    const int wm = w >> 1, wn = w & 1;
    const int quad = l >> 4, ln = l & 15;
    const int s_blk = blockIdx.x * 128;
    const unsigned char* cb = (const unsigned char*)tcity;
    const unsigned char* pb = (const unsigned char*)tprov;
    // byte -> bf16x8 lookup (bit j -> element j as 0.0/1.0)
    __shared__ __align__(16) __bf16 lut[256][8];
    __shared__ u32 lastv;
    {
        #pragma unroll
        for (int j = 0; j < 8; ++j)
            lut[t][j] = ((t >> j) & 1) ? (__bf16)1.0f : (__bf16)0.0f;
    }
    __syncthreads();
    const f32x4 fz = {0.0f, 0.0f, 0.0f, 0.0f};
    f32x4 acc[4][4];
    #pragma unroll
    for (int mt = 0; mt < 4; ++mt)
        #pragma unroll
        for (int nt = 0; nt < 4; ++nt) acc[mt][nt] = fz;
    const int k_base = blockIdx.y * 512;
    for (int it = 0; it < 16; ++it) {
        int kk = k_base + it * 32;
        bf16x8 Ya[4], Za[4];
        #pragma unroll
        for (int mt = 0; mt < 4; ++mt) {
            int f = wm * 64 + mt * 16 + ln;
            Ya[mt] = *(const bf16x8*)(YT + f * B_N + kk + quad * 8);
            Za[mt] = *(const bf16x8*)(ZT + f * B_N + kk + quad * 8);
        }
        bf16x8 Bc[4], Bp[4];
        #pragma unroll
        for (int nt = 0; nt < 4; ++nt) {
            int s = s_blk + wn * 64 + nt * 16 + ln;
            size_t base = ((size_t)(kk >> 6) * MPAD + s) * 8 + ((kk >> 3) & 7) + quad;
            unsigned int cby = cb[base], pby = pb[base];
            Bc[nt] = *(const bf16x8*)(&lut[cby][0]);
            Bp[nt] = *(const bf16x8*)(&lut[pby][0]);
        }
        #pragma unroll
        for (int mt = 0; mt < 4; ++mt)
            #pragma unroll
            for (int nt = 0; nt < 4; ++nt) {
                acc[mt][nt] = __builtin_amdgcn_mfma_f32_16x16x32_bf16(Ya[mt], Bc[nt], acc[mt][nt], 0, 0, 0);
                acc[mt][nt] = __builtin_amdgcn_mfma_f32_16x16x32_bf16(Za[mt], Bp[nt], acc[mt][nt], 0, 0, 0);
            }
    }
    float* tp = Tp + (size_t)blockIdx.y * ((size_t)MPAD * F_N);
    #pragma unroll
    for (int nt = 0; nt < 4; ++nt) {
        int s = s_blk + wn * 64 + nt * 16 + ln;
        #pragma unroll
        for (int mt = 0; mt < 4; ++mt) {
            int f0 = wm * 64 + mt * 16 + quad * 4;
            *(f32x4*)(tp + (size_t)s * F_N + f0) = acc[mt][nt];
        }
    }
    // split-K ticket: last block of this s-tile reduces partials -> Tb
    __syncthreads();
    if (t == 0) {
        __threadfence();
        lastv = atomicAdd(&tick[blockIdx.x], 1u);
    }
    __syncthreads();
    if (lastv == 3u) {
        __threadfence();
        const size_t stride = (size_t)MPAD * F_N;
        for (int idx = t; idx < 4096; idx += 256) {
            size_t off = (size_t)s_blk * F_N + (size_t)idx * 4;
            f32x4 v0 = *(const f32x4*)(Tp + off);
            f32x4 v1 = *(const f32x4*)(Tp + stride + off);
            f32x4 v2 = *(const f32x4*)(Tp + 2 * stride + off);
            f32x4 v3 = *(const f32x4*)(Tp + 3 * stride + off);
            f32x4 sum = v0 + v1 + v2 + v3;
            bf16x4 o;
            #pragma unroll
            for (int j = 0; j < 4; ++j) o[j] = (__bf16)sum[j];
            *(bf16x4*)(Tb + off) = o;
        }
    }
}

// ---------------- G2: h2 GEMM + att softmax + fused M-partial MFMA ----------------
__global__ __launch_bounds__(256) void g_h2attM(const __bf16* __restrict__ A, const __bf16* __restrict__ W2T,
        const float* __restrict__ a, const float* __restrict__ q, const int* __restrict__ inter,
        __bf16* __restrict__ attb, float* __restrict__ Mg) {
    const int t = threadIdx.x, l = t & 63, w = t >> 6;
    const int wm = w >> 1, wn = w & 1, quad = l >> 4, ln = l & 15;
    const int s0 = blockIdx.x * 128, h = blockIdx.y;
    __shared__ __bf16 h2T[128 * 136];   // [f][s_local], stride 136
    __shared__ __bf16 attT[16 * 136];   // [c][s_local]
    __shared__ float ps[128];
    if (t < 128) ps[t] = 0.0f;
    __syncthreads();
    const f32x4 fz = {0.0f, 0.0f, 0.0f, 0.0f};
    f32x4 acc[4][4];
    #pragma unroll
    for (int mt = 0; mt < 4; ++mt)
        #pragma unroll
        for (int nt = 0; nt < 4; ++nt) acc[mt][nt] = fz;
    #pragma unroll
    for (int it = 0; it < 4; ++it) {
        int kk = it * 32;
        bf16x8 af[4], bfr[4];
        #pragma unroll
        for (int mt = 0; mt < 4; ++mt)
            af[mt] = *(const bf16x8*)(A + (size_t)(s0 + wm * 64 + mt * 16 + ln) * F_N + kk + quad * 8);
        #pragma unroll
        for (int nt = 0; nt < 4; ++nt)
            bfr[nt] = *(const bf16x8*)(W2T + (size_t)(h * F_N + wn * 64 + nt * 16 + ln) * F_N + kk + quad * 8);
        #pragma unroll
        for (int mt = 0; mt < 4; ++mt)
            #pragma unroll
            for (int nt = 0; nt < 4; ++nt)
                acc[mt][nt] = __builtin_amdgcn_mfma_f32_16x16x32_bf16(af[mt], bfr[nt], acc[mt][nt], 0, 0, 0);
    }
    float a2v[4];
    #pragma unroll
    for (int nt = 0; nt < 4; ++nt) a2v[nt] = a[h * 256 + 128 + wn * 64 + nt * 16 + ln];
    #pragma unroll
    for (int mt = 0; mt < 4; ++mt) {
        #pragma unroll
        for (int nt = 0; nt < 4; ++nt) {
            bf16x4 o;
            #pragma unroll
            for (int j = 0; j < 4; ++j) o[j] = (__bf16)acc[mt][nt][j];
            *(bf16x4*)(&h2T[(wn * 64 + nt * 16 + ln) * 136 + wm * 64 + mt * 16 + quad * 4]) = o;
        }
        #pragma unroll
        for (int r = 0; r < 4; ++r) {
            float pp = 0.0f;
            #pragma unroll
            for (int nt = 0; nt < 4; ++nt) pp += acc[mt][nt][r] * a2v[nt];
            #pragma unroll
            for (int m = 8; m > 0; m >>= 1) pp += __shfl_xor(pp, m, 16);
            if (ln == 0) atomicAdd(&ps[wm * 64 + mt * 16 + quad * 4 + r], pp);
        }
    }
    __syncthreads();
    if (t < 128) {
        int s = s0 + t;
        if (s < S_N) {
            float pv = ps[t];
            float e[16];
            int msk[16], cn = 0;
            float mx = -3e38f;
            #pragma unroll
            for (int c = 0; c < 16; ++c) {
                msk[c] = inter[s * 16 + c] > 0;
                cn += msk[c];
                e[c] = lrelu02(pv + q[h * 16 + c]);
                if (msk[c]) mx = fmaxf(mx, e[c]);
            }
            float sm = 0.0f;
            #pragma unroll
            for (int c = 0; c < 16; ++c) {
                e[c] = msk[c] ? expf(e[c] - mx) : 0.0f;
                sm += e[c];
            }
            float inv = cn > 0 ? 1.0f / sm : 0.0f;
            #pragma unroll
            for (int c = 0; c < 16; ++c) {
                float av = cn > 0 ? e[c] * inv : 0.0625f;
                attb[((size_t)h * MPAD + s) * 16 + c] = (__bf16)av;
                attT[c * 136 + t] = (__bf16)av;
            }
        } else {
            #pragma unroll
            for (int c = 0; c < 16; ++c) {
                attb[((size_t)h * MPAD + s) * 16 + c] = (__bf16)0.0f;
                attT[c * 136 + t] = (__bf16)0.0f;
            }
        }
    }
    __syncthreads();
    #pragma unroll
    for (int fi = 0; fi < 2; ++fi) {
        int ft = 2 * w + fi;
        f32x4 macc = fz;
        #pragma unroll
        for (int kit = 0; kit < 4; ++kit) {
            bf16x8 av = *(const bf16x8*)(&attT[ln * 136 + kit * 32 + quad * 8]);
            bf16x8 bv = *(const bf16x8*)(&h2T[(ft * 16 + ln) * 136 + kit * 32 + quad * 8]);
            macc = __builtin_amdgcn_mfma_f32_16x16x32_bf16(av, bv, macc, 0, 0, 0);
        }
        #pragma unroll
        for (int r = 0; r < 4; ++r)
            atomicAdd(&Mg[(h * 16 + quad * 4 + r) * F_N + ft * 16 + ln], macc[r]);
    }
}

// ---------------- G3: P = T@W2 + att@h1 (bf16, LDS-staged store) + BN column sums ---------
__global__ __launch_bounds__(256) void g_P(const __bf16* __restrict__ Tb, const __bf16* __restrict__ W2T,
        const __bf16* __restrict__ attb, const __bf16* __restrict__ h1T,
        __bf16* __restrict__ P, float* __restrict__ usum, float* __restrict__ usq) {
    const int t = threadIdx.x, l = t & 63, w = t >> 6;
    const int wm = w >> 1, wn = w & 1, quad = l >> 4, ln = l & 15;
    const int s0 = blockIdx.x * 128, h = blockIdx.y;
    __shared__ __bf16 sP[128 * 136];
    __shared__ float lsum[128], lsq[128];
    if (t < 128) { lsum[t] = 0.0f; lsq[t] = 0.0f; }
    __syncthreads();
    const f32x4 fz = {0.0f, 0.0f, 0.0f, 0.0f};
    f32x4 acc[4][4];
    #pragma unroll
    for (int mt = 0; mt < 4; ++mt)
        #pragma unroll
        for (int nt = 0; nt < 4; ++nt) acc[mt][nt] = fz;
    {
        bf16x8 a2[4], b2[4];
        #pragma unroll
        for (int mt = 0; mt < 4; ++mt) {
            int s = s0 + wm * 64 + mt * 16 + ln;
            Bh8 az;
            az.v = *(const bf16x8*)(attb + ((size_t)h * MPAD + s) * 16 + (quad & 1) * 8);
            if (quad >= 2) {
                #pragma unroll
                for (int j = 0; j < 8; ++j) az.h[j] = (__bf16)0.0f;
            }
            a2[mt] = az.v;
        }
        #pragma unroll
        for (int nt = 0; nt < 4; ++nt) {
            int f = wn * 64 + nt * 16 + ln;
            b2[nt] = *(const bf16x8*)(h1T + ((size_t)(h * F_N + f)) * 32 + quad * 8);
        }
        #pragma unroll
        for (int mt = 0; mt < 4; ++mt)
            #pragma unroll
            for (int nt = 0; nt < 4; ++nt)
                acc[mt][nt] = __builtin_amdgcn_mfma_f32_16x16x32_bf16(a2[mt], b2[nt], acc[mt][nt], 0, 0, 0);
    }
    #pragma unroll
    for (int it = 0; it < 4; ++it) {
        int kk = it * 32;
        bf16x8 af[4], bfr[4];
        #pragma unroll
        for (int mt = 0; mt < 4; ++mt)
            af[mt] = *(const bf16x8*)(Tb + (size_t)(s0 + wm * 64 + mt * 16 + ln) * F_N + kk + quad * 8);
        #pragma unroll
        for (int nt = 0; nt < 4; ++nt)
            bfr[nt] = *(const bf16x8*)(W2T + (size_t)(h * F_N + wn * 64 + nt * 16 + ln) * F_N + kk + quad * 8);
        #pragma unroll
        for (int mt = 0; mt < 4; ++mt)
            #pragma unroll
            for (int nt = 0; nt < 4; ++nt)
                acc[mt][nt] = __builtin_amdgcn_mfma_f32_16x16x32_bf16(af[mt], bfr[nt], acc[mt][nt], 0, 0, 0);
    }
    #pragma unroll
    for (int nt = 0; nt < 4; ++nt) {
        int f = wn * 64 + nt * 16 + ln;
        float p1 = 0.0f, p2 = 0.0f;
        #pragma unroll
        for (int mt = 0; mt < 4; ++mt) {
            int sb = wm * 64 + mt * 16 + quad * 4;
            #pragma unroll
            for (int r = 0; r < 4; ++r) {
                float val = acc[mt][nt][r];
                sP[(sb + r) * 136 + f] = (__bf16)val;
                p1 += val; p2 += val * val;
            }
        }
        atomicAdd(&lsum[f], p1);
        atomicAdd(&lsq[f], p2);
    }
    __syncthreads();
    if (t < 128) {
        atomicAdd(&usum[h * F_N + t], lsum[t]);
        atomicAdd(&usq[h * F_N + t], lsq[t]);
    }
    for (int g = t; g < 2048; g += 256) {
        int sl = g >> 4, fg = (g & 15) * 8;
        bf16x8 v = *(const bf16x8*)(&sP[sl * 136 + fg]);
        *(bf16x8*)(P + ((size_t)h * MPAD + s0 + sl) * F_N + fg) = v;
    }
}

// ---------------- G4: bn-finalize + G=elu(u@v^T) + final GAT layer + log_softmax ------
__global__ __launch_bounds__(256) void g_out(const __bf16* __restrict__ P,
        const float* __restrict__ usum, const float* __restrict__ usq, const float* __restrict__ Mg,
        const float* __restrict__ g1, const float* __restrict__ b1,
        const float* __restrict__ g2, const float* __restrict__ b2,
        const float* __restrict__ outW, const int* __restrict__ inter, float* __restrict__ out) {
    const int t = threadIdx.x, l = t & 63, w = t >> 6, quad = l >> 4, ln = l & 15;
    const int s0 = blockIdx.x * 32;
    __shared__ __bf16 v_lds[64 * 136];   // [h*16+r][f]
    __shared__ float G_lds[32 * 68];     // [s_local][h*16+r]
    __shared__ float scs[512], shs[512];
    __shared__ float W_lds[1024];
    for (int i = t; i < 1024; i += 256) W_lds[i] = outW[i];
    if (t < 128) {
        #pragma unroll
        for (int h = 0; h < 4; ++h) {
            int i = h * F_N + t;
            float mean = usum[i] * (1.0f / S_N);
            float var = usq[i] * (1.0f / S_N) - mean * mean;
            float sc = g2[i] * rsqrtf(var + 1e-5f);
            scs[i] = sc;
            shs[i] = b2[i] - mean * sc;
        }
    }
    {   // v = lrelu(bn1(M))
        int f = t & 127;
        int hb = (t >> 7) * 2;
        #pragma unroll
        for (int hh = hb; hh < hb + 2; ++hh) {
            float mv[16], sa = 0.0f, sb = 0.0f;
            #pragma unroll
            for (int r = 0; r < 16; ++r) {
                mv[r] = Mg[(hh * 16 + r) * F_N + f];
                sa += mv[r]; sb += mv[r] * mv[r];
            }
            float m1 = sa * 0.0625f, v1 = sb * 0.0625f - m1 * m1;
            int i = hh * F_N + f;
            float g = g1[i] * rsqrtf(v1 + 1e-5f);
            float bb = b1[i] - m1 * g;
            #pragma unroll
            for (int r = 0; r < 16; ++r)
                v_lds[(hh * 16 + r) * 136 + f] = (__bf16)lrelu02(mv[r] * g + bb);
        }
    }
    __syncthreads();
    const int h = w;
    const f32x4 fz = {0.0f, 0.0f, 0.0f, 0.0f};
    #pragma unroll
    for (int mt = 0; mt < 2; ++mt) {
        f32x4 gacc = fz;
        int s = s0 + mt * 16 + ln;
        #pragma unroll
        for (int kit = 0; kit < 4; ++kit) {
            int k0 = kit * 32 + quad * 8;
            bf16x8 pv = *(const bf16x8*)(P + ((size_t)h * MPAD + s) * F_N + k0);
            Bh8 af;
            #pragma unroll
            for (int j = 0; j < 8; ++j) {
                int f = k0 + j;
                af.h[j] = (__bf16)lrelu02((float)pv[j] * scs[h * F_N + f] + shs[h * F_N + f]);
            }
            bf16x8 bv = *(const bf16x8*)(&v_lds[(h * 16 + ln) * 136 + k0]);
            gacc = __builtin_amdgcn_mfma_f32_16x16x32_bf16(af.v, bv, gacc, 0, 0, 0);
        }
        #pragma unroll
        for (int r = 0; r < 4; ++r)
            G_lds[(mt * 16 + quad * 4 + r) * 68 + h * 16 + ln] = eluf(gacc[r]);
    }
    __syncthreads();
    const int c = t & 15, ss = t >> 4;
    #pragma unroll
    for (int pass = 0; pass < 2; ++pass) {
        int sl = pass * 16 + ss;
        int s = s0 + sl;
        float hm = 0.0f;
        #pragma unroll
        for (int j = 0; j < 64; ++j) hm += G_lds[sl * 68 + j] * W_lds[j * 16 + c];
        int valid = s < S_N;
        int msk = valid ? (inter[(valid ? s : 0) * 16 + c] > 0) : 0;
        int cn = msk;
        #pragma unroll
        for (int m = 8; m > 0; m >>= 1) cn += __shfl_xor(cn, m, 16);
        float attf = cn > 0 ? (msk ? 1.0f / (float)cn : 0.0f) : 0.0625f;
        float y = eluf(eluf(attf * hm));
        float mx = y;
        #pragma unroll
        for (int m = 8; m > 0; m >>= 1) mx = fmaxf(mx, __shfl_xor(mx, m, 16));
        float ex = expf(y - mx);
        float sm = ex;
        #pragma unroll
        for (int m = 8; m > 0; m >>= 1) sm += __shfl_xor(sm, m, 16);
        if (valid) out[s * 16 + c] = y - mx - logf(sm);
    }
}

extern "C" void kernel_launch(void* const* d_in, const int* in_sizes, int n_in,
                              void* d_out, int out_size, void* d_ws, size_t ws_size,
                              hipStream_t stream) {
    const int* inter = (const int*)d_in[0];
    const int* city  = (const int*)d_in[1];
    const int* prov  = (const int*)d_in[2];
    const int* src   = (const int*)d_in[3];
    const float* Sfeat = (const float*)d_in[4];
    const float* Rfeat = (const float*)d_in[5];
    const float* W1 = (const float*)d_in[6];
    const float* W2 = (const float*)d_in[7];
    const float* a  = (const float*)d_in[8];
    const float* g1 = (const float*)d_in[11];
    const float* b1 = (const float*)d_in[12];
    const float* g2 = (const float*)d_in[13];
    const float* b2 = (const float*)d_in[14];
    const float* outW = (const float*)d_in[15];
    float* out = (float*)d_out;

    char* p = (char*)d_ws;
    // ---- zeroed region ----
    float* M    = (float*)p; p += 4 * 16 * F_N * 4;   // 32768
    float* usum = (float*)p; p += 2048;
    float* usq  = (float*)p; p += 2048;
    u32*   cc   = (u32*)p;   p += 8192;
    u32*   pc   = (u32*)p;   p += 8192;
    u32*   tick = (u32*)p;   p += 512;                // 79 used
    size_t zbytes = (size_t)(p - (char*)d_ws);        // 53760
    // ---- rest ----
    u64* tcity = (u64*)p; p += 32 * (size_t)MPAD * 8;
    u64* tprov = (u64*)p; p += 32 * (size_t)MPAD * 8;
    __bf16* YT  = (__bf16*)p; p += (size_t)F_N * B_N * 2;
    __bf16* ZT  = (__bf16*)p; p += (size_t)F_N * B_N * 2;
    __bf16* SfB = (__bf16*)p; p += (size_t)MPAD * F_N * 2;
    __bf16* W2T = (__bf16*)p; p += 512 * 128 * 2;
    __bf16* h1T = (__bf16*)p; p += 4 * 128 * 32 * 2;
    float*  q   = (float*)p;  p += 512;
    float*  Tp  = (float*)p;  p += 4 * (size_t)MPAD * F_N * 4;
    __bf16* Tb  = (__bf16*)p; p += (size_t)MPAD * F_N * 2;
    __bf16* attb= (__bf16*)p; p += 4 * (size_t)MPAD * 16 * 2;
    __bf16* P   = (__bf16*)p; p += 4 * (size_t)MPAD * F_N * 2;

    hipMemsetAsync(d_ws, 0, zbytes, stream);
    k_bits_pre<<<6656, 256, 0, stream>>>(city, prov, src, Sfeat, Rfeat, W1, W2, a,
                                         tcity, tprov, cc, pc, SfB, W2T, h1T, q);
    k_yz      <<<1024, 256, 0, stream>>>(Sfeat, src, cc, pc, YT, ZT);
    g_T       <<<dim3(79, 4), 256, 0, stream>>>(YT, ZT, tcity, tprov, Tp, tick, Tb);
    g_h2attM  <<<dim3(79, 4), 256, 0, stream>>>(SfB, W2T, a, q, inter, attb, M);
    g_P       <<<dim3(79, 4), 256, 0, stream>>>(Tb, W2T, attb, h1T, P, usum, usq);
    g_out     <<<316, 256, 0, stream>>>(P, usum, usq, M, g1, b1, g2, b2, outW, inter, out);
}

// Round 7
// 769.336 us; speedup vs baseline: 1.1098x; 1.0443x over previous
//
#include <hip/hip_runtime.h>
#include <hip/hip_bf16.h>
#include <stdint.h>

#define S_N 10000
#define MPAD 10112
#define B_N 2048
#define F_N 128

typedef __bf16 bf16x8 __attribute__((ext_vector_type(8)));
typedef __bf16 bf16x4 __attribute__((ext_vector_type(4)));
typedef float  f32x4  __attribute__((ext_vector_type(4)));
typedef unsigned long long u64;
typedef unsigned int u32;
typedef unsigned short u16;

union Bf8 { u16 us[8]; bf16x8 v; };
union Bh8 { __bf16 h[8]; bf16x8 v; };

__device__ __forceinline__ float lrelu02(float x) { return x >= 0.0f ? x : 0.2f * x; }
__device__ __forceinline__ float eluf(float x)    { return x > 0.0f ? x : expm1f(x); }

// ---------------- K1: adjacency gather (direct bit-transposed build) + SfB + W2T + h1T/q ----
// blocks 0..1279: mask gather; 1280..6335: SfB; 6336..6591: W2T; 6592..6655: h1T/q
__global__ __launch_bounds__(256) void k_bits_pre(const int* __restrict__ adj_c,
        const int* __restrict__ adj_p, const int* __restrict__ src,
        const float* __restrict__ Sfeat, const float* __restrict__ Rfeat,
        const float* __restrict__ W1, const float* __restrict__ W2, const float* __restrict__ a,
        u64* __restrict__ tcity, u64* __restrict__ tprov,
        u32* __restrict__ cc, u32* __restrict__ pc,
        __bf16* __restrict__ SfB, __bf16* __restrict__ W2T, __bf16* __restrict__ h1T,
        float* __restrict__ q) {
    const int bid = blockIdx.x, t = threadIdx.x;
    if (bid < 1280) {
        // lane owns 2 s-values; build the u64 (bits over 64 batch rows) in-register.
        const int sc = bid % 20, wb = (bid / 20) % 32, mat = bid / 640;
        const int l = t & 63;
        const int* adj = mat ? adj_p : adj_c;
        u64* tb = mat ? tprov : tcity;
        u32* cnt = mat ? pc : cc;
        __shared__ u32 lc[64];
        if (t < 64) lc[t] = 0;
        __syncthreads();
        const int s1 = sc * 512 + 2 * t;       // s1 even; covers s1, s1+1
        const int in_rng = (s1 < S_N);
        const int* base0 = adj + s1;
        u64 w1 = 0, w2 = 0;
        #pragma unroll 8
        for (int bb = 0; bb < 64; ++bb) {
            int row = src[wb * 64 + bb];
            int vx = 0, vy = 0;
            if (in_rng) {
                int2 v = *(const int2*)(base0 + (size_t)row * S_N);
                vx = v.x; vy = v.y;
            }
            u64 b1 = __ballot(vx > 0);
            u64 b2 = __ballot(vy > 0);
            w1 |= (u64)(vx > 0 ? 1u : 0u) << bb;
            w2 |= (u64)(vy > 0 ? 1u : 0u) << bb;
            if (l == 0) atomicAdd(&lc[bb], (u32)(__popcll(b1) + __popcll(b2)));
        }
        __syncthreads();
        if (t < 64) atomicAdd(&cnt[wb * 64 + t], lc[t]);
        if (s1 < MPAD) {
            u64* dst = tb + (size_t)wb * MPAD + s1;
            dst[0] = w1;
            dst[1] = w2;
        }
    } else if (bid < 6336) {
        int i = (bid - 1280) * 256 + t; // MPAD*128
        int s = i >> 7;
        SfB[i] = (__bf16)(s < S_N ? Sfeat[i] : 0.0f);
    } else if (bid < 6592) {
        int idx = (bid - 6336) * 256 + t; // 65536
        int hn = idx >> 7, k = idx & 127;
        int h = hn >> 7, n = hn & 127;
        W2T[idx] = (__bf16)W2[(h * F_N + k) * F_N + n];
    } else {
        __shared__ float red[256];
        int b2i = bid - 6592;
        int h = b2i >> 4, r = b2i & 15;
        float hv = 0.0f;
        if (t < 128) {
            const float* rf = Rfeat + r * F_N;
            const float* wp = W1 + h * F_N * F_N + t;
            for (int k = 0; k < F_N; ++k) hv += rf[k] * wp[k * F_N];
        }
        red[t] = (t < 128) ? hv * a[h * 256 + t] : 0.0f;
        __syncthreads();
        for (int off = 128; off > 0; off >>= 1) {
            if (t < off) red[t] += red[t + off];
            __syncthreads();
        }
        if (t == 0) q[h * 16 + r] = red[0];
        if (t < 128) {
            h1T[(h * F_N + t) * 32 + r] = (__bf16)hv;
            h1T[(h * F_N + t) * 32 + 16 + r] = (__bf16)0.0f;
        }
    }
}

// ---------------- K2: Y^T/Z^T (needs counts from K1) ----------------
__global__ __launch_bounds__(256) void k_yz(const float* __restrict__ Sfeat,
        const int* __restrict__ src, const u32* __restrict__ cc, const u32* __restrict__ pc,
        __bf16* __restrict__ YT, __bf16* __restrict__ ZT) {
    int idx = blockIdx.x * 256 + threadIdx.x; // 128*2048
    int f = idx >> 11, b = idx & 2047;
    float sv = Sfeat[src[b] * F_N + f];
    float icc = cc[b] ? 1.0f / (float)cc[b] : 0.0f;
    float ipc = pc[b] ? 1.0f / (float)pc[b] : 0.0f;
    YT[f * B_N + b] = (__bf16)(sv * icc);
    ZT[f * B_N + b] = (__bf16)(sv * ipc);
}

// ---------------- G1: T split-K partials (VALU unpack) + ticketed reduce -> Tb ---------
__global__ __launch_bounds__(256) void g_T(const __bf16* __restrict__ YT, const __bf16* __restrict__ ZT,
        const u64* __restrict__ tcity, const u64* __restrict__ tprov,
        float* __restrict__ Tp, u32* __restrict__ tick, __bf16* __restrict__ Tb) {
    const int t = threadIdx.x, l = t & 63, w = t >> 6;
    const int wm = w >> 1, wn = w & 1;
    const int quad = l >> 4, ln = l & 15;
    const int s_blk = blockIdx.x * 128;
    const unsigned char* cb = (const unsigned char*)tcity;
    const unsigned char* pb = (const unsigned char*)tprov;
    __shared__ u32 lastv;
    const f32x4 fz = {0.0f, 0.0f, 0.0f, 0.0f};
    f32x4 acc[4][4];
    #pragma unroll
    for (int mt = 0; mt < 4; ++mt)
        #pragma unroll
        for (int nt = 0; nt < 4; ++nt) acc[mt][nt] = fz;
    const int k_base = blockIdx.y * 512;
    for (int it = 0; it < 16; ++it) {
        int kk = k_base + it * 32;
        bf16x8 Ya[4], Za[4];
        #pragma unroll
        for (int mt = 0; mt < 4; ++mt) {
            int f = wm * 64 + mt * 16 + ln;
            Ya[mt] = *(const bf16x8*)(YT + f * B_N + kk + quad * 8);
            Za[mt] = *(const bf16x8*)(ZT + f * B_N + kk + quad * 8);
        }
        bf16x8 Bc[4], Bp[4];
        #pragma unroll
        for (int nt = 0; nt < 4; ++nt) {
            int s = s_blk + wn * 64 + nt * 16 + ln;
            size_t base = ((size_t)(kk >> 6) * MPAD + s) * 8 + ((kk >> 3) & 7) + quad;
            unsigned int cby = cb[base], pby = pb[base];
            Bf8 uc, up;
            #pragma unroll
            for (int j = 0; j < 8; ++j) {
                uc.us[j] = ((cby >> j) & 1u) ? (u16)0x3F80 : (u16)0;
                up.us[j] = ((pby >> j) & 1u) ? (u16)0x3F80 : (u16)0;
            }
            Bc[nt] = uc.v; Bp[nt] = up.v;
        }
        #pragma unroll
        for (int mt = 0; mt < 4; ++mt)
            #pragma unroll
            for (int nt = 0; nt < 4; ++nt) {
                acc[mt][nt] = __builtin_amdgcn_mfma_f32_16x16x32_bf16(Ya[mt], Bc[nt], acc[mt][nt], 0, 0, 0);
                acc[mt][nt] = __builtin_amdgcn_mfma_f32_16x16x32_bf16(Za[mt], Bp[nt], acc[mt][nt], 0, 0, 0);
            }
    }
    float* tp = Tp + (size_t)blockIdx.y * ((size_t)MPAD * F_N);
    #pragma unroll
    for (int nt = 0; nt < 4; ++nt) {
        int s = s_blk + wn * 64 + nt * 16 + ln;
        #pragma unroll
        for (int mt = 0; mt < 4; ++mt) {
            int f0 = wm * 64 + mt * 16 + quad * 4;
            *(f32x4*)(tp + (size_t)s * F_N + f0) = acc[mt][nt];
        }
    }
    // split-K ticket: last block of this s-tile reduces partials -> Tb
    __syncthreads();
    if (t == 0) {
        __threadfence();
        lastv = atomicAdd(&tick[blockIdx.x], 1u);
    }
    __syncthreads();
    if (lastv == 3u) {
        __threadfence();
        const size_t stride = (size_t)MPAD * F_N;
        for (int idx = t; idx < 4096; idx += 256) {
            size_t off = (size_t)s_blk * F_N + (size_t)idx * 4;
            f32x4 v0 = *(const f32x4*)(Tp + off);
            f32x4 v1 = *(const f32x4*)(Tp + stride + off);
            f32x4 v2 = *(const f32x4*)(Tp + 2 * stride + off);
            f32x4 v3 = *(const f32x4*)(Tp + 3 * stride + off);
            f32x4 sum = v0 + v1 + v2 + v3;
            bf16x4 o;
            #pragma unroll
            for (int j = 0; j < 4; ++j) o[j] = (__bf16)sum[j];
            *(bf16x4*)(Tb + off) = o;
        }
    }
}

// ---------------- G2: h2 GEMM + att softmax + fused M-partial MFMA ----------------
__global__ __launch_bounds__(256) void g_h2attM(const __bf16* __restrict__ A, const __bf16* __restrict__ W2T,
        const float* __restrict__ a, const float* __restrict__ q, const int* __restrict__ inter,
        __bf16* __restrict__ attb, float* __restrict__ Mg) {
    const int t = threadIdx.x, l = t & 63, w = t >> 6;
    const int wm = w >> 1, wn = w & 1, quad = l >> 4, ln = l & 15;
    const int s0 = blockIdx.x * 128, h = blockIdx.y;
    __shared__ __bf16 h2T[128 * 136];   // [f][s_local], stride 136
    __shared__ __bf16 attT[16 * 136];   // [c][s_local]
    __shared__ float ps[128];
    if (t < 128) ps[t] = 0.0f;
    __syncthreads();
    const f32x4 fz = {0.0f, 0.0f, 0.0f, 0.0f};
    f32x4 acc[4][4];
    #pragma unroll
    for (int mt = 0; mt < 4; ++mt)
        #pragma unroll
        for (int nt = 0; nt < 4; ++nt) acc[mt][nt] = fz;
    #pragma unroll
    for (int it = 0; it < 4; ++it) {
        int kk = it * 32;
        bf16x8 af[4], bfr[4];
        #pragma unroll
        for (int mt = 0; mt < 4; ++mt)
            af[mt] = *(const bf16x8*)(A + (size_t)(s0 + wm * 64 + mt * 16 + ln) * F_N + kk + quad * 8);
        #pragma unroll
        for (int nt = 0; nt < 4; ++nt)
            bfr[nt] = *(const bf16x8*)(W2T + (size_t)(h * F_N + wn * 64 + nt * 16 + ln) * F_N + kk + quad * 8);
        #pragma unroll
        for (int mt = 0; mt < 4; ++mt)
            #pragma unroll
            for (int nt = 0; nt < 4; ++nt)
                acc[mt][nt] = __builtin_amdgcn_mfma_f32_16x16x32_bf16(af[mt], bfr[nt], acc[mt][nt], 0, 0, 0);
    }
    float a2v[4];
    #pragma unroll
    for (int nt = 0; nt < 4; ++nt) a2v[nt] = a[h * 256 + 128 + wn * 64 + nt * 16 + ln];
    #pragma unroll
    for (int mt = 0; mt < 4; ++mt) {
        #pragma unroll
        for (int nt = 0; nt < 4; ++nt) {
            bf16x4 o;
            #pragma unroll
            for (int j = 0; j < 4; ++j) o[j] = (__bf16)acc[mt][nt][j];
            *(bf16x4*)(&h2T[(wn * 64 + nt * 16 + ln) * 136 + wm * 64 + mt * 16 + quad * 4]) = o;
        }
        #pragma unroll
        for (int r = 0; r < 4; ++r) {
            float pp = 0.0f;
            #pragma unroll
            for (int nt = 0; nt < 4; ++nt) pp += acc[mt][nt][r] * a2v[nt];
            #pragma unroll
            for (int m = 8; m > 0; m >>= 1) pp += __shfl_xor(pp, m, 16);
            if (ln == 0) atomicAdd(&ps[wm * 64 + mt * 16 + quad * 4 + r], pp);
        }
    }
    __syncthreads();
    if (t < 128) {
        int s = s0 + t;
        if (s < S_N) {
            float pv = ps[t];
            float e[16];
            int msk[16], cn = 0;
            float mx = -3e38f;
            #pragma unroll
            for (int c = 0; c < 16; ++c) {
                msk[c] = inter[s * 16 + c] > 0;
                cn += msk[c];
                e[c] = lrelu02(pv + q[h * 16 + c]);
                if (msk[c]) mx = fmaxf(mx, e[c]);
            }
            float sm = 0.0f;
            #pragma unroll
            for (int c = 0; c < 16; ++c) {
                e[c] = msk[c] ? expf(e[c] - mx) : 0.0f;
                sm += e[c];
            }
            float inv = cn > 0 ? 1.0f / sm : 0.0f;
            #pragma unroll
            for (int c = 0; c < 16; ++c) {
                float av = cn > 0 ? e[c] * inv : 0.0625f;
                attb[((size_t)h * MPAD + s) * 16 + c] = (__bf16)av;
                attT[c * 136 + t] = (__bf16)av;
            }
        } else {
            #pragma unroll
            for (int c = 0; c < 16; ++c) {
                attb[((size_t)h * MPAD + s) * 16 + c] = (__bf16)0.0f;
                attT[c * 136 + t] = (__bf16)0.0f;
            }
        }
    }
    __syncthreads();
    #pragma unroll
    for (int fi = 0; fi < 2; ++fi) {
        int ft = 2 * w + fi;
        f32x4 macc = fz;
        #pragma unroll
        for (int kit = 0; kit < 4; ++kit) {
            bf16x8 av = *(const bf16x8*)(&attT[ln * 136 + kit * 32 + quad * 8]);
            bf16x8 bv = *(const bf16x8*)(&h2T[(ft * 16 + ln) * 136 + kit * 32 + quad * 8]);
            macc = __builtin_amdgcn_mfma_f32_16x16x32_bf16(av, bv, macc, 0, 0, 0);
        }
        #pragma unroll
        for (int r = 0; r < 4; ++r)
            atomicAdd(&Mg[(h * 16 + quad * 4 + r) * F_N + ft * 16 + ln], macc[r]);
    }
}

// ---------------- G3: P = T@W2 + att@h1 (bf16, LDS-staged store) + BN column sums ---------
__global__ __launch_bounds__(256) void g_P(const __bf16* __restrict__ Tb, const __bf16* __restrict__ W2T,
        const __bf16* __restrict__ attb, const __bf16* __restrict__ h1T,
        __bf16* __restrict__ P, float* __restrict__ usum, float* __restrict__ usq) {
    const int t = threadIdx.x, l = t & 63, w = t >> 6;
    const int wm = w >> 1, wn = w & 1, quad = l >> 4, ln = l & 15;
    const int s0 = blockIdx.x * 128, h = blockIdx.y;
    __shared__ __bf16 sP[128 * 136];
    __shared__ float lsum[128], lsq[128];
    if (t < 128) { lsum[t] = 0.0f; lsq[t] = 0.0f; }
    __syncthreads();
    const f32x4 fz = {0.0f, 0.0f, 0.0f, 0.0f};
    f32x4 acc[4][4];
    #pragma unroll
    for (int mt = 0; mt < 4; ++mt)
        #pragma unroll
        for (int nt = 0; nt < 4; ++nt) acc[mt][nt] = fz;
    {
        bf16x8 a2[4], b2[4];
        #pragma unroll
        for (int mt = 0; mt < 4; ++mt) {
            int s = s0 + wm * 64 + mt * 16 + ln;
            Bh8 az;
            az.v = *(const bf16x8*)(attb + ((size_t)h * MPAD + s) * 16 + (quad & 1) * 8);
            if (quad >= 2) {
                #pragma unroll
                for (int j = 0; j < 8; ++j) az.h[j] = (__bf16)0.0f;
            }
            a2[mt] = az.v;
        }
        #pragma unroll
        for (int nt = 0; nt < 4; ++nt) {
            int f = wn * 64 + nt * 16 + ln;
            b2[nt] = *(const bf16x8*)(h1T + ((size_t)(h * F_N + f)) * 32 + quad * 8);
        }
        #pragma unroll
        for (int mt = 0; mt < 4; ++mt)
            #pragma unroll
            for (int nt = 0; nt < 4; ++nt)
                acc[mt][nt] = __builtin_amdgcn_mfma_f32_16x16x32_bf16(a2[mt], b2[nt], acc[mt][nt], 0, 0, 0);
    }
    #pragma unroll
    for (int it = 0; it < 4; ++it) {
        int kk = it * 32;
        bf16x8 af[4], bfr[4];
        #pragma unroll
        for (int mt = 0; mt < 4; ++mt)
            af[mt] = *(const bf16x8*)(Tb + (size_t)(s0 + wm * 64 + mt * 16 + ln) * F_N + kk + quad * 8);
        #pragma unroll
        for (int nt = 0; nt < 4; ++nt)
            bfr[nt] = *(const bf16x8*)(W2T + (size_t)(h * F_N + wn * 64 + nt * 16 + ln) * F_N + kk + quad * 8);
        #pragma unroll
        for (int mt = 0; mt < 4; ++mt)
            #pragma unroll
            for (int nt = 0; nt < 4; ++nt)
                acc[mt][nt] = __builtin_amdgcn_mfma_f32_16x16x32_bf16(af[mt], bfr[nt], acc[mt][nt], 0, 0, 0);
    }
    #pragma unroll
    for (int nt = 0; nt < 4; ++nt) {
        int f = wn * 64 + nt * 16 + ln;
        float p1 = 0.0f, p2 = 0.0f;
        #pragma unroll
        for (int mt = 0; mt < 4; ++mt) {
            int sb = wm * 64 + mt * 16 + quad * 4;
            #pragma unroll
            for (int r = 0; r < 4; ++r) {
                float val = acc[mt][nt][r];
                sP[(sb + r) * 136 + f] = (__bf16)val;
                p1 += val; p2 += val * val;
            }
        }
        atomicAdd(&lsum[f], p1);
        atomicAdd(&lsq[f], p2);
    }
    __syncthreads();
    if (t < 128) {
        atomicAdd(&usum[h * F_N + t], lsum[t]);
        atomicAdd(&usq[h * F_N + t], lsq[t]);
    }
    for (int g = t; g < 2048; g += 256) {
        int sl = g >> 4, fg = (g & 15) * 8;
        bf16x8 v = *(const bf16x8*)(&sP[sl * 136 + fg]);
        *(bf16x8*)(P + ((size_t)h * MPAD + s0 + sl) * F_N + fg) = v;
    }
}

// ---------------- G4: bn-finalize + G=elu(u@v^T) + final GAT layer + log_softmax ------
__global__ __launch_bounds__(256) void g_out(const __bf16* __restrict__ P,
        const float* __restrict__ usum, const float* __restrict__ usq, const float* __restrict__ Mg,
        const float* __restrict__ g1, const float* __restrict__ b1,
        const float* __restrict__ g2, const float* __restrict__ b2,
        const float* __restrict__ outW, const int* __restrict__ inter, float* __restrict__ out) {
    const int t = threadIdx.x, l = t & 63, w = t >> 6, quad = l >> 4, ln = l & 15;
    const int s0 = blockIdx.x * 32;
    __shared__ __bf16 v_lds[64 * 136];   // [h*16+r][f]
    __shared__ float G_lds[32 * 68];     // [s_local][h*16+r]
    __shared__ float scs[512], shs[512];
    __shared__ float W_lds[1024];
    for (int i = t; i < 1024; i += 256) W_lds[i] = outW[i];
    if (t < 128) {
        #pragma unroll
        for (int h = 0; h < 4; ++h) {
            int i = h * F_N + t;
            float mean = usum[i] * (1.0f / S_N);
            float var = usq[i] * (1.0f / S_N) - mean * mean;
            float sc = g2[i] * rsqrtf(var + 1e-5f);
            scs[i] = sc;
            shs[i] = b2[i] - mean * sc;
        }
    }
    {   // v = lrelu(bn1(M))
        int f = t & 127;
        int hb = (t >> 7) * 2;
        #pragma unroll
        for (int hh = hb; hh < hb + 2; ++hh) {
            float mv[16], sa = 0.0f, sb = 0.0f;
            #pragma unroll
            for (int r = 0; r < 16; ++r) {
                mv[r] = Mg[(hh * 16 + r) * F_N + f];
                sa += mv[r]; sb += mv[r] * mv[r];
            }
            float m1 = sa * 0.0625f, v1 = sb * 0.0625f - m1 * m1;
            int i = hh * F_N + f;
            float g = g1[i] * rsqrtf(v1 + 1e-5f);
            float bb = b1[i] - m1 * g;
            #pragma unroll
            for (int r = 0; r < 16; ++r)
                v_lds[(hh * 16 + r) * 136 + f] = (__bf16)lrelu02(mv[r] * g + bb);
        }
    }
    __syncthreads();
    const int h = w;
    const f32x4 fz = {0.0f, 0.0f, 0.0f, 0.0f};
    #pragma unroll
    for (int mt = 0; mt < 2; ++mt) {
        f32x4 gacc = fz;
        int s = s0 + mt * 16 + ln;
        #pragma unroll
        for (int kit = 0; kit < 4; ++kit) {
            int k0 = kit * 32 + quad * 8;
            bf16x8 pv = *(const bf16x8*)(P + ((size_t)h * MPAD + s) * F_N + k0);
            Bh8 af;
            #pragma unroll
            for (int j = 0; j < 8; ++j) {
                int f = k0 + j;
                af.h[j] = (__bf16)lrelu02((float)pv[j] * scs[h * F_N + f] + shs[h * F_N + f]);
            }
            bf16x8 bv = *(const bf16x8*)(&v_lds[(h * 16 + ln) * 136 + k0]);
            gacc = __builtin_amdgcn_mfma_f32_16x16x32_bf16(af.v, bv, gacc, 0, 0, 0);
        }
        #pragma unroll
        for (int r = 0; r < 4; ++r)
            G_lds[(mt * 16 + quad * 4 + r) * 68 + h * 16 + ln] = eluf(gacc[r]);
    }
    __syncthreads();
    const int c = t & 15, ss = t >> 4;
    #pragma unroll
    for (int pass = 0; pass < 2; ++pass) {
        int sl = pass * 16 + ss;
        int s = s0 + sl;
        float hm = 0.0f;
        #pragma unroll
        for (int j = 0; j < 64; ++j) hm += G_lds[sl * 68 + j] * W_lds[j * 16 + c];
        int valid = s < S_N;
        int msk = valid ? (inter[(valid ? s : 0) * 16 + c] > 0) : 0;
        int cn = msk;
        #pragma unroll
        for (int m = 8; m > 0; m >>= 1) cn += __shfl_xor(cn, m, 16);
        float attf = cn > 0 ? (msk ? 1.0f / (float)cn : 0.0f) : 0.0625f;
        float y = eluf(eluf(attf * hm));
        float mx = y;
        #pragma unroll
        for (int m = 8; m > 0; m >>= 1) mx = fmaxf(mx, __shfl_xor(mx, m, 16));
        float ex = expf(y - mx);
        float sm = ex;
        #pragma unroll
        for (int m = 8; m > 0; m >>= 1) sm += __shfl_xor(sm, m, 16);
        if (valid) out[s * 16 + c] = y - mx - logf(sm);
    }
}

extern "C" void kernel_launch(void* const* d_in, const int* in_sizes, int n_in,
                              void* d_out, int out_size, void* d_ws, size_t ws_size,
                              hipStream_t stream) {
    const int* inter = (const int*)d_in[0];
    const int* city  = (const int*)d_in[1];
    const int* prov  = (const int*)d_in[2];
    const int* src   = (const int*)d_in[3];
    const float* Sfeat = (const float*)d_in[4];
    const float* Rfeat = (const float*)d_in[5];
    const float* W1 = (const float*)d_in[6];
    const float* W2 = (const float*)d_in[7];
    const float* a  = (const float*)d_in[8];
    const float* g1 = (const float*)d_in[11];
    const float* b1 = (const float*)d_in[12];
    const float* g2 = (const float*)d_in[13];
    const float* b2 = (const float*)d_in[14];
    const float* outW = (const float*)d_in[15];
    float* out = (float*)d_out;

    char* p = (char*)d_ws;
    // ---- zeroed region ----
    float* M    = (float*)p; p += 4 * 16 * F_N * 4;   // 32768
    float* usum = (float*)p; p += 2048;
    float* usq  = (float*)p; p += 2048;
    u32*   cc   = (u32*)p;   p += 8192;
    u32*   pc   = (u32*)p;   p += 8192;
    u32*   tick = (u32*)p;   p += 512;                // 79 used
    size_t zbytes = (size_t)(p - (char*)d_ws);        // 53760
    // ---- rest ----
    u64* tcity = (u64*)p; p += 32 * (size_t)MPAD * 8;
    u64* tprov = (u64*)p; p += 32 * (size_t)MPAD * 8;
    __bf16* YT  = (__bf16*)p; p += (size_t)F_N * B_N * 2;
    __bf16* ZT  = (__bf16*)p; p += (size_t)F_N * B_N * 2;
    __bf16* SfB = (__bf16*)p; p += (size_t)MPAD * F_N * 2;
    __bf16* W2T = (__bf16*)p; p += 512 * 128 * 2;
    __bf16* h1T = (__bf16*)p; p += 4 * 128 * 32 * 2;
    float*  q   = (float*)p;  p += 512;
    float*  Tp  = (float*)p;  p += 4 * (size_t)MPAD * F_N * 4;
    __bf16* Tb  = (__bf16*)p; p += (size_t)MPAD * F_N * 2;
    __bf16* attb= (__bf16*)p; p += 4 * (size_t)MPAD * 16 * 2;
    __bf16* P   = (__bf16*)p; p += 4 * (size_t)MPAD * F_N * 2;

    hipMemsetAsync(d_ws, 0, zbytes, stream);
    k_bits_pre<<<6656, 256, 0, stream>>>(city, prov, src, Sfeat, Rfeat, W1, W2, a,
                                         tcity, tprov, cc, pc, SfB, W2T, h1T, q);
    k_yz      <<<1024, 256, 0, stream>>>(Sfeat, src, cc, pc, YT, ZT);
    g_T       <<<dim3(79, 4), 256, 0, stream>>>(YT, ZT, tcity, tprov, Tp, tick, Tb);
    g_h2attM  <<<dim3(79, 4), 256, 0, stream>>>(SfB, W2T, a, q, inter, attb, M);
    g_P       <<<dim3(79, 4), 256, 0, stream>>>(Tb, W2T, attb, h1T, P, usum, usq);
    g_out     <<<316, 256, 0, stream>>>(P, usum, usq, M, g1, b1, g2, b2, outW, inter, out);
}